// Round 1
// baseline (484.178 us; speedup 1.0000x reference)
//
#include <hip/hip_runtime.h>
#include <math.h>

#define BH  16384   // half batch
#define B2  32768
#define DIM 256
#define KC  1024    // clusters

typedef __bf16 bf16x8 __attribute__((ext_vector_type(8)));
typedef float  f32x4  __attribute__((ext_vector_type(4)));

__device__ __forceinline__ unsigned short f2bf(float f) {
  unsigned int u = __float_as_uint(f);
  u += 0x7FFFu + ((u >> 16) & 1u);   // RNE; inputs are finite
  return (unsigned short)(u >> 16);
}

__device__ __forceinline__ float dist_L(float dotv) {
  // L = D/eps = 20*sqrt(max(2-2*dot, 1e-12))
  return 20.0f * sqrtf(fmaxf(2.0f - 2.0f * dotv, 1e-12f));
}

// one wave per row: l2-normalize and convert to bf16
__global__ void norm_rows_kernel(const float* __restrict__ z,
                                 const float* __restrict__ p,
                                 const float* __restrict__ c,
                                 unsigned short* __restrict__ Xn,
                                 unsigned short* __restrict__ Pn,
                                 unsigned short* __restrict__ Cn) {
  int wave = threadIdx.x >> 6;
  int lane = threadIdx.x & 63;
  int row  = blockIdx.x * 4 + wave;          // 0 .. 66559
  const float* src; unsigned short* dst; int r;
  if (row < B2)        { src = z; dst = Xn; r = row; }
  else if (row < 2*B2) { src = p; dst = Pn; r = row - B2; }
  else                 { src = c; dst = Cn; r = row - 2*B2; }
  float4 v = *reinterpret_cast<const float4*>(src + (size_t)r * DIM + lane * 4);
  float ss = v.x*v.x + v.y*v.y + v.z*v.z + v.w*v.w;
  #pragma unroll
  for (int m = 1; m < 64; m <<= 1) ss += __shfl_xor(ss, m);
  float inv = 1.0f / fmaxf(sqrtf(ss), 1e-12f);
  ushort4 o;
  o.x = f2bf(v.x * inv); o.y = f2bf(v.y * inv);
  o.z = f2bf(v.z * inv); o.w = f2bf(v.w * inv);
  *reinterpret_cast<ushort4*>(dst + (size_t)r * DIM + lane * 4) = o;
}

__global__ void zero_kernel(float* __restrict__ colsum,
                            float* __restrict__ rowsum,
                            float* __restrict__ out) {
  int i = blockIdx.x * 256 + threadIdx.x;
  if (i < 4 * KC) colsum[i] = 0.0f;
  if (i < 4 * BH) rowsum[i] = 0.0f;
  if (i == 0)     out[0]    = 0.0f;
}

__global__ void fin_logC_kernel(const float* __restrict__ colsum,
                                float* __restrict__ logC) {
  int i = blockIdx.x * 256 + threadIdx.x;
  if (i < 4 * KC) logC[i] = 40.0f + logf(colsum[i]);
}

__global__ void fin_lse_kernel(const float* __restrict__ rowsum,
                               float* __restrict__ lse) {
  int i = blockIdx.x * 256 + threadIdx.x;
  if (i < 4 * BH) lse[i] = logf(rowsum[i]);  // G <= 0, no extra shift needed
}

// PASS 0: colsum[m][k] += sum_b exp(L-40)
// PASS 1: rowsum[m][b] += sum_k exp(L - logC[k])
// PASS 2: out += -(1/4B) * sum (za1+za2)*(logpa1+logpa2)
template<int PASS>
__global__ __launch_bounds__(256)
void pass_kernel(const unsigned short* __restrict__ Xn,
                 const unsigned short* __restrict__ Pn,
                 const unsigned short* __restrict__ Cn,
                 float* __restrict__ colsum,
                 const float* __restrict__ logC,
                 float* __restrict__ rowsum,
                 const float* __restrict__ lse,
                 float* __restrict__ out) {
  __shared__ __align__(16) char lds[65536];  // Cs [0,32KB), Xs [32KB,64KB)
  const int tn0  = blockIdx.x * 64;          // cluster tile base
  const int tm0  = blockIdx.y * 64;          // batch tile base
  const int tid  = threadIdx.x;
  const int lane = tid & 63;
  const int w    = tid >> 6;
  const int wm   = w >> 1, wn = w & 1;
  const int l15  = lane & 15, l4 = lane >> 4;

  // stage C tile (rows tn0..tn0+63), swizzled: byte ^= (row&7)<<4
  #pragma unroll
  for (int it = 0; it < 8; ++it) {
    int cidx = it * 256 + tid;
    int r = cidx >> 5, c8 = cidx & 31;
    float4 v = *reinterpret_cast<const float4*>(
        reinterpret_cast<const char*>(Cn) + (size_t)(tn0 + r) * 512 + c8 * 16);
    *reinterpret_cast<float4*>(lds + (r * 512 + ((c8 * 16) ^ ((r & 7) << 4)))) = v;
  }

  float wv[2][2][4];  // za1+za2 (PASS 2)
  float tv[2][2][4];  // logpa1+logpa2 (PASS 2)
  if (PASS == 2) {
    #pragma unroll
    for (int a = 0; a < 2; ++a)
      #pragma unroll
      for (int b = 0; b < 2; ++b)
        #pragma unroll
        for (int i = 0; i < 4; ++i) { wv[a][b][i] = 0.f; tv[a][b][i] = 0.f; }
  }

  for (int m = 0; m < 4; ++m) {
    const unsigned short* Xm = (m < 2)
        ? (Xn + (size_t)(m * BH + tm0) * DIM)
        : (Pn + (size_t)((m - 2) * BH + tm0) * DIM);
    __syncthreads();   // previous compute done before overwriting Xs
    #pragma unroll
    for (int it = 0; it < 8; ++it) {
      int cidx = it * 256 + tid;
      int r = cidx >> 5, c8 = cidx & 31;
      float4 v = *reinterpret_cast<const float4*>(
          reinterpret_cast<const char*>(Xm) + (size_t)r * 512 + c8 * 16);
      *reinterpret_cast<float4*>(lds + 32768 +
          (r * 512 + ((c8 * 16) ^ ((r & 7) << 4)))) = v;
    }
    __syncthreads();

    f32x4 acc[2][2] = {};
    #pragma unroll
    for (int ks = 0; ks < 8; ++ks) {
      const int kb = (ks * 32 + l4 * 8) * 2;   // byte offset of 8-bf16 chunk
      bf16x8 aF[2], bF[2];
      #pragma unroll
      for (int f = 0; f < 2; ++f) {
        int ra = wm * 32 + f * 16 + l15;
        aF[f] = *reinterpret_cast<const bf16x8*>(
            lds + 32768 + (ra * 512 + (kb ^ ((ra & 7) << 4))));
        int rb = wn * 32 + f * 16 + l15;
        bF[f] = *reinterpret_cast<const bf16x8*>(
            lds + (rb * 512 + (kb ^ ((rb & 7) << 4))));
      }
      #pragma unroll
      for (int fi = 0; fi < 2; ++fi)
        #pragma unroll
        for (int fj = 0; fj < 2; ++fj)
          acc[fi][fj] = __builtin_amdgcn_mfma_f32_16x16x32_bf16(
              aF[fi], bF[fj], acc[fi][fj], 0, 0, 0);
    }

    if (PASS == 0) {
      #pragma unroll
      for (int fj = 0; fj < 2; ++fj) {
        float cp = 0.f;
        #pragma unroll
        for (int fi = 0; fi < 2; ++fi)
          #pragma unroll
          for (int i = 0; i < 4; ++i)
            cp += __expf(dist_L(acc[fi][fj][i]) - 40.0f);
        cp += __shfl_xor(cp, 16);
        cp += __shfl_xor(cp, 32);
        if (l4 == 0)
          atomicAdd(&colsum[m * KC + tn0 + wn * 32 + fj * 16 + l15], cp);
      }
    } else if (PASS == 1) {
      float rp[2][4] = {};
      #pragma unroll
      for (int fj = 0; fj < 2; ++fj) {
        float lc = logC[m * KC + tn0 + wn * 32 + fj * 16 + l15];
        #pragma unroll
        for (int fi = 0; fi < 2; ++fi)
          #pragma unroll
          for (int i = 0; i < 4; ++i)
            rp[fi][i] += __expf(dist_L(acc[fi][fj][i]) - lc);
      }
      #pragma unroll
      for (int fi = 0; fi < 2; ++fi)
        #pragma unroll
        for (int i = 0; i < 4; ++i) {
          float v = rp[fi][i];
          v += __shfl_xor(v, 1); v += __shfl_xor(v, 2);
          v += __shfl_xor(v, 4); v += __shfl_xor(v, 8);
          if (l15 == 0)
            atomicAdd(&rowsum[m * BH + tm0 + wm * 32 + fi * 16 + l4 * 4 + i], v);
        }
    } else {
      #pragma unroll
      for (int fj = 0; fj < 2; ++fj) {
        float lc = logC[m * KC + tn0 + wn * 32 + fj * 16 + l15];
        #pragma unroll
        for (int fi = 0; fi < 2; ++fi)
          #pragma unroll
          for (int i = 0; i < 4; ++i) {
            float ls = lse[m * BH + tm0 + wm * 32 + fi * 16 + l4 * 4 + i];
            float G = dist_L(acc[fi][fj][i]) - lc - ls;
            if (m < 2) wv[fi][fj][i] += __expf(G);
            else       tv[fi][fj][i] += G;
          }
      }
    }
  }

  if (PASS == 2) {
    float s = 0.f;
    #pragma unroll
    for (int a = 0; a < 2; ++a)
      #pragma unroll
      for (int b = 0; b < 2; ++b)
        #pragma unroll
        for (int i = 0; i < 4; ++i)
          s += wv[a][b][i] * tv[a][b][i];
    s += __shfl_xor(s, 1);  s += __shfl_xor(s, 2);  s += __shfl_xor(s, 4);
    s += __shfl_xor(s, 8);  s += __shfl_xor(s, 16); s += __shfl_xor(s, 32);
    if (lane == 0)
      atomicAdd(out, s * (-1.0f / 65536.0f));   // 1/(4*BH)
  }
}

extern "C" void kernel_launch(void* const* d_in, const int* in_sizes, int n_in,
                              void* d_out, int out_size, void* d_ws, size_t ws_size,
                              hipStream_t stream) {
  const float* z = (const float*)d_in[0];
  const float* p = (const float*)d_in[1];
  const float* c = (const float*)d_in[2];
  char* ws = (char*)d_ws;
  // layout (bytes): Xn 16.78MB | Pn 16.78MB | Cn 0.5MB | colsum | logC | rowsum | lse
  unsigned short* Xn = (unsigned short*)(ws);
  unsigned short* Pn = (unsigned short*)(ws + 16777216);
  unsigned short* Cn = (unsigned short*)(ws + 33554432);
  float* colsum = (float*)(ws + 34078720);
  float* logC   = (float*)(ws + 34095104);
  float* rowsum = (float*)(ws + 34111488);
  float* lse    = (float*)(ws + 34373632);
  float* out = (float*)d_out;

  norm_rows_kernel<<<16640, 256, 0, stream>>>(z, p, c, Xn, Pn, Cn);
  zero_kernel<<<256, 256, 0, stream>>>(colsum, rowsum, out);

  dim3 grid(KC / 64, BH / 64);  // (16, 256)
  pass_kernel<0><<<grid, 256, 0, stream>>>(Xn, Pn, Cn, colsum, logC, rowsum, lse, out);
  fin_logC_kernel<<<16, 256, 0, stream>>>(colsum, logC);
  pass_kernel<1><<<grid, 256, 0, stream>>>(Xn, Pn, Cn, colsum, logC, rowsum, lse, out);
  fin_lse_kernel<<<256, 256, 0, stream>>>(rowsum, lse);
  pass_kernel<2><<<grid, 256, 0, stream>>>(Xn, Pn, Cn, colsum, logC, rowsum, lse, out);
}

// Round 2
// 316.765 us; speedup vs baseline: 1.5285x; 1.5285x over previous
//
#include <hip/hip_runtime.h>
#include <math.h>

#define BH  16384   // half batch
#define B2  32768
#define DIM 256
#define KC  1024    // clusters

typedef __bf16 bf16x8 __attribute__((ext_vector_type(8)));
typedef float  f32x4  __attribute__((ext_vector_type(4)));

__device__ __forceinline__ unsigned short f2bf(float f) {
  unsigned int u = __float_as_uint(f);
  u += 0x7FFFu + ((u >> 16) & 1u);   // RNE; inputs are finite
  return (unsigned short)(u >> 16);
}

__device__ __forceinline__ float dist_L(float dotv) {
  // L = D/eps = 20*sqrt(max(2-2*dot, 1e-12))
  return 20.0f * sqrtf(fmaxf(2.0f - 2.0f * dotv, 1e-12f));
}

__device__ __forceinline__ void gld_lds16(const void* g, void* l) {
  __builtin_amdgcn_global_load_lds(
      (const __attribute__((address_space(1))) void*)g,
      (__attribute__((address_space(3))) void*)l, 16, 0, 0);
}

// one wave per row: l2-normalize and convert to bf16
__global__ void norm_rows_kernel(const float* __restrict__ z,
                                 const float* __restrict__ p,
                                 const float* __restrict__ c,
                                 unsigned short* __restrict__ Xn,
                                 unsigned short* __restrict__ Pn,
                                 unsigned short* __restrict__ Cn) {
  int wave = threadIdx.x >> 6;
  int lane = threadIdx.x & 63;
  int row  = blockIdx.x * 4 + wave;          // 0 .. 66559
  const float* src; unsigned short* dst; int r;
  if (row < B2)        { src = z; dst = Xn; r = row; }
  else if (row < 2*B2) { src = p; dst = Pn; r = row - B2; }
  else                 { src = c; dst = Cn; r = row - 2*B2; }
  float4 v = *reinterpret_cast<const float4*>(src + (size_t)r * DIM + lane * 4);
  float ss = v.x*v.x + v.y*v.y + v.z*v.z + v.w*v.w;
  #pragma unroll
  for (int m = 1; m < 64; m <<= 1) ss += __shfl_xor(ss, m);
  float inv = 1.0f / fmaxf(sqrtf(ss), 1e-12f);
  ushort4 o;
  o.x = f2bf(v.x * inv); o.y = f2bf(v.y * inv);
  o.z = f2bf(v.z * inv); o.w = f2bf(v.w * inv);
  *reinterpret_cast<ushort4*>(dst + (size_t)r * DIM + lane * 4) = o;
}

__global__ void zero_kernel(float* __restrict__ colsum,
                            float* __restrict__ rowsum,
                            float* __restrict__ out) {
  int i = blockIdx.x * 256 + threadIdx.x;
  if (i < 4 * KC) colsum[i] = 0.0f;
  if (i < 4 * BH) rowsum[i] = 0.0f;
  if (i == 0)     out[0]    = 0.0f;
}

__global__ void fin_logC_kernel(const float* __restrict__ colsum,
                                float* __restrict__ logC) {
  int i = blockIdx.x * 256 + threadIdx.x;
  if (i < 4 * KC) logC[i] = 40.0f + logf(colsum[i]);
}

// lse = log(rowsum); also fold the separated +2/(4B)*sum(lse_p1+lse_p2) term
__global__ void fin_lse_kernel(const float* __restrict__ rowsum,
                               float* __restrict__ lse,
                               float* __restrict__ out) {
  int i = blockIdx.x * 256 + threadIdx.x;
  float v = 0.0f;
  if (i < 4 * BH) { v = logf(rowsum[i]); lse[i] = v; }
  float c = (i >= 2 * BH && i < 4 * BH) ? v : 0.0f;
  #pragma unroll
  for (int m = 1; m < 64; m <<= 1) c += __shfl_xor(c, m);
  if ((threadIdx.x & 63) == 0)
    atomicAdd(out, c * (2.0f / 65536.0f));
}

// Matrix order inside block: mi=0..3 -> mat {2(p1),3(p2),0(z1),1(z2)}
// PASS 0: colsum[mat][k] += sum_b exp(L-40)
// PASS 1: rowsum[mat][b] += sum_k exp(L - logC[k])
// PASS 2: out += -(1/4B) * sum_k exp(G_z - lse_z) * (G_p1 + G_p2)
template<int PASS>
__global__ __launch_bounds__(256, 2)
void pass_kernel(const unsigned short* __restrict__ XA,  // [4][BH][DIM]
                 const unsigned short* __restrict__ Cn,  // [KC][DIM]
                 float* __restrict__ colsum,
                 const float* __restrict__ logC,
                 float* __restrict__ rowsum,
                 const float* __restrict__ lse,
                 float* __restrict__ out) {
  __shared__ __align__(16) char lds[65536];  // A: 2x16KB at 0; B: 2x16KB at 32768
  const int tn0  = blockIdx.x * 128;
  const int tm0  = blockIdx.y * 128;
  const int tid  = threadIdx.x;
  const int lane = tid & 63;
  const int w    = tid >> 6;
  const int wm   = w >> 1, wn = w & 1;
  const int l15  = lane & 15, l4 = lane >> 4;

  // staging slots: tile = 128 rows x 64 bf16 (128B) = 1024 slots of 16B
  int arow[4], acs[4];
  #pragma unroll
  for (int it = 0; it < 4; ++it) {
    int slot = it * 256 + tid;
    int r = slot >> 3, c = slot & 7;
    arow[it] = r;
    acs[it]  = c ^ (r & 7);    // pre-swizzled source chunk (involution)
  }
  const char* cb = (const char*)Cn;

  auto stage = [&](int t) {
    const int mat = ((t >> 2) + 2) & 3;
    const int ks  = t & 3;
    const int b   = t & 1;
    const char* ab = (const char*)XA + ((size_t)mat * BH + tm0) * 512;
    #pragma unroll
    for (int it = 0; it < 4; ++it) {
      gld_lds16(ab + (size_t)arow[it] * 512 + ks * 128 + acs[it] * 16,
                lds + b * 16384 + (it * 256 + tid) * 16);
      gld_lds16(cb + (size_t)(tn0 + arow[it]) * 512 + ks * 128 + acs[it] * 16,
                lds + 32768 + b * 16384 + (it * 256 + tid) * 16);
    }
  };

  f32x4 acc[4][4];
  float tv[4][4][4];   // PASS 2: G_p1+G_p2 held across matrix loop
  float s2 = 0.0f;     // PASS 2 scalar accumulator

  stage(0);
  __syncthreads();

  for (int t = 0; t < 16; ++t) {
    if (t < 15) stage(t + 1);
    const int b  = t & 1;
    const int mi = t >> 2, ks = t & 3;
    const int mat = (mi + 2) & 3;

    if (ks == 0) {
      #pragma unroll
      for (int fi = 0; fi < 4; ++fi)
        #pragma unroll
        for (int fj = 0; fj < 4; ++fj)
          acc[fi][fj] = (f32x4){0.f, 0.f, 0.f, 0.f};
    }

    #pragma unroll
    for (int kc = 0; kc < 2; ++kc) {
      bf16x8 aF[4], bF[4];
      #pragma unroll
      for (int f = 0; f < 4; ++f) {
        const int ra = wm * 64 + f * 16 + l15;
        aF[f] = *reinterpret_cast<const bf16x8*>(
            lds + b * 16384 + ra * 128 + (((((kc << 2) | l4)) ^ (ra & 7)) << 4));
        const int rb = wn * 64 + f * 16 + l15;
        bF[f] = *reinterpret_cast<const bf16x8*>(
            lds + 32768 + b * 16384 + rb * 128 + (((((kc << 2) | l4)) ^ (rb & 7)) << 4));
      }
      #pragma unroll
      for (int fi = 0; fi < 4; ++fi)
        #pragma unroll
        for (int fj = 0; fj < 4; ++fj)
          acc[fi][fj] = __builtin_amdgcn_mfma_f32_16x16x32_bf16(
              aF[fi], bF[fj], acc[fi][fj], 0, 0, 0);
    }

    if (ks == 3) {
      if (PASS == 0) {
        #pragma unroll
        for (int fj = 0; fj < 4; ++fj) {
          float cp = 0.0f;
          #pragma unroll
          for (int fi = 0; fi < 4; ++fi)
            #pragma unroll
            for (int i = 0; i < 4; ++i)
              cp += __expf(dist_L(acc[fi][fj][i]) - 40.0f);
          cp += __shfl_xor(cp, 16);
          cp += __shfl_xor(cp, 32);
          if (l4 == 0)
            atomicAdd(&colsum[mat * KC + tn0 + wn * 64 + fj * 16 + l15], cp);
        }
      } else if (PASS == 1) {
        float lc[4];
        #pragma unroll
        for (int fj = 0; fj < 4; ++fj)
          lc[fj] = logC[mat * KC + tn0 + wn * 64 + fj * 16 + l15];
        #pragma unroll
        for (int fi = 0; fi < 4; ++fi)
          #pragma unroll
          for (int i = 0; i < 4; ++i) {
            float rp = 0.0f;
            #pragma unroll
            for (int fj = 0; fj < 4; ++fj)
              rp += __expf(dist_L(acc[fi][fj][i]) - lc[fj]);
            rp += __shfl_xor(rp, 1); rp += __shfl_xor(rp, 2);
            rp += __shfl_xor(rp, 4); rp += __shfl_xor(rp, 8);
            if (l15 == 0)
              atomicAdd(&rowsum[mat * BH + tm0 + wm * 64 + fi * 16 + l4 * 4 + i], rp);
          }
      } else {
        float lc[4];
        #pragma unroll
        for (int fj = 0; fj < 4; ++fj)
          lc[fj] = logC[mat * KC + tn0 + wn * 64 + fj * 16 + l15];
        if (mi < 2) {          // p1 (mi=0) sets tv, p2 (mi=1) adds
          #pragma unroll
          for (int fi = 0; fi < 4; ++fi)
            #pragma unroll
            for (int fj = 0; fj < 4; ++fj)
              #pragma unroll
              for (int i = 0; i < 4; ++i) {
                float G = dist_L(acc[fi][fj][i]) - lc[fj];
                tv[fi][fj][i] = (mi == 0) ? G : (tv[fi][fj][i] + G);
              }
        } else {               // z1, z2: fold weights immediately
          #pragma unroll
          for (int fi = 0; fi < 4; ++fi)
            #pragma unroll
            for (int i = 0; i < 4; ++i) {
              float ls = lse[mat * BH + tm0 + wm * 64 + fi * 16 + l4 * 4 + i];
              #pragma unroll
              for (int fj = 0; fj < 4; ++fj)
                s2 += __expf(dist_L(acc[fi][fj][i]) - lc[fj] - ls) * tv[fi][fj][i];
            }
        }
      }
    }
    __syncthreads();
  }

  if (PASS == 2) {
    s2 += __shfl_xor(s2, 1);  s2 += __shfl_xor(s2, 2);  s2 += __shfl_xor(s2, 4);
    s2 += __shfl_xor(s2, 8);  s2 += __shfl_xor(s2, 16); s2 += __shfl_xor(s2, 32);
    if (lane == 0)
      atomicAdd(out, s2 * (-1.0f / 65536.0f));   // -1/(4*BH)
  }
}

extern "C" void kernel_launch(void* const* d_in, const int* in_sizes, int n_in,
                              void* d_out, int out_size, void* d_ws, size_t ws_size,
                              hipStream_t stream) {
  const float* z = (const float*)d_in[0];
  const float* p = (const float*)d_in[1];
  const float* c = (const float*)d_in[2];
  char* ws = (char*)d_ws;
  // layout: XA = [z1,z2,p1,p2] bf16 (33.55MB) | Cn 0.5MB | colsum | logC | rowsum | lse
  unsigned short* Xn = (unsigned short*)(ws);
  unsigned short* Pn = (unsigned short*)(ws + 16777216);
  unsigned short* Cn = (unsigned short*)(ws + 33554432);
  float* colsum = (float*)(ws + 34078720);
  float* logC   = (float*)(ws + 34095104);
  float* rowsum = (float*)(ws + 34111488);
  float* lse    = (float*)(ws + 34373632);
  float* out = (float*)d_out;

  norm_rows_kernel<<<16640, 256, 0, stream>>>(z, p, c, Xn, Pn, Cn);
  zero_kernel<<<256, 256, 0, stream>>>(colsum, rowsum, out);

  dim3 grid(KC / 128, BH / 128);  // (8, 128) = 1024 blocks
  pass_kernel<0><<<grid, 256, 0, stream>>>(Xn, Cn, colsum, logC, rowsum, lse, out);
  fin_logC_kernel<<<16, 256, 0, stream>>>(colsum, logC);
  pass_kernel<1><<<grid, 256, 0, stream>>>(Xn, Cn, colsum, logC, rowsum, lse, out);
  fin_lse_kernel<<<256, 256, 0, stream>>>(rowsum, lse, out);
  pass_kernel<2><<<grid, 256, 0, stream>>>(Xn, Cn, colsum, logC, rowsum, lse, out);
}

// Round 3
// 222.329 us; speedup vs baseline: 2.1778x; 1.4248x over previous
//
#include <hip/hip_runtime.h>
#include <math.h>

#define BH  16384   // half batch
#define B2  32768
#define DIM 256
#define KC  1024    // clusters

typedef __bf16 bf16x8 __attribute__((ext_vector_type(8)));
typedef float  f32x4  __attribute__((ext_vector_type(4)));

__device__ __forceinline__ unsigned short f2bf(float f) {
  unsigned int u = __float_as_uint(f);
  u += 0x7FFFu + ((u >> 16) & 1u);   // RNE; inputs are finite
  return (unsigned short)(u >> 16);
}

__device__ __forceinline__ float vsqrt(float x) {
  float r; asm("v_sqrt_f32 %0, %1" : "=v"(r) : "v"(x)); return r;
}

__device__ __forceinline__ float dist_L(float dotv) {
  // L = D/eps = 20*sqrt(max(2-2*dot, 1e-12))
  return 20.0f * vsqrt(fmaxf(2.0f - 2.0f * dotv, 1e-12f));
}

__device__ __forceinline__ void gld_lds16(const void* g, void* l) {
  __builtin_amdgcn_global_load_lds(
      (const __attribute__((address_space(1))) void*)g,
      (__attribute__((address_space(3))) void*)l, 16, 0, 0);
}

// one wave per row: l2-normalize and convert to bf16
__global__ void norm_rows_kernel(const float* __restrict__ z,
                                 const float* __restrict__ p,
                                 const float* __restrict__ c,
                                 unsigned short* __restrict__ Xn,
                                 unsigned short* __restrict__ Cn) {
  int wave = threadIdx.x >> 6;
  int lane = threadIdx.x & 63;
  int row  = blockIdx.x * 4 + wave;          // 0 .. 66559
  const float* src; unsigned short* dst; int r;
  if (row < B2)        { src = z; dst = Xn; r = row; }
  else if (row < 2*B2) { src = p; dst = Xn + (size_t)B2 * DIM; r = row - B2; }
  else                 { src = c; dst = Cn; r = row - 2*B2; }
  float4 v = *reinterpret_cast<const float4*>(src + (size_t)r * DIM + lane * 4);
  float ss = v.x*v.x + v.y*v.y + v.z*v.z + v.w*v.w;
  #pragma unroll
  for (int m = 1; m < 64; m <<= 1) ss += __shfl_xor(ss, m);
  float inv = 1.0f / fmaxf(vsqrt(ss), 1e-12f);
  ushort4 o;
  o.x = f2bf(v.x * inv); o.y = f2bf(v.y * inv);
  o.z = f2bf(v.z * inv); o.w = f2bf(v.w * inv);
  *reinterpret_cast<ushort4*>(dst + (size_t)r * DIM + lane * 4) = o;
}

__global__ void zero_kernel(float* __restrict__ colsum,
                            float* __restrict__ rowAux,
                            float* __restrict__ out) {
  int i = blockIdx.x * 256 + threadIdx.x;
  if (i < 6 * BH) rowAux[i] = 0.0f;
  if (i < 4 * KC) colsum[i] = 0.0f;
  if (i == 0)     out[0]    = 0.0f;
}

__global__ void fin_logC_kernel(const float* __restrict__ colsum,
                                float* __restrict__ logC) {
  int i = blockIdx.x * 256 + threadIdx.x;
  if (i < 4 * KC) logC[i] = 40.0f + __logf(colsum[i]);
}

// loss = -(1/4B) * sum_b [num_z1/den_z1 + num_z2/den_z2 - 2(log den_p1 + log den_p2)]
__global__ void fin_loss_kernel(const float* __restrict__ rowAux,
                                float* __restrict__ out) {
  int i = blockIdx.x * 256 + threadIdx.x;   // 64 blocks x 256 = BH
  const float* denP1 = rowAux;
  const float* denP2 = rowAux + BH;
  const float* denZ1 = rowAux + 2 * BH;
  const float* denZ2 = rowAux + 3 * BH;
  const float* numZ1 = rowAux + 4 * BH;
  const float* numZ2 = rowAux + 5 * BH;
  float v = numZ1[i] / denZ1[i] + numZ2[i] / denZ2[i]
          - 2.0f * (__logf(denP1[i]) + __logf(denP2[i]));
  #pragma unroll
  for (int m = 1; m < 64; m <<= 1) v += __shfl_xor(v, m);
  __shared__ float ws[4];
  int lane = threadIdx.x & 63, wid = threadIdx.x >> 6;
  if (lane == 0) ws[wid] = v;
  __syncthreads();
  if (threadIdx.x == 0)
    atomicAdd(out, (ws[0] + ws[1] + ws[2] + ws[3]) * (-1.0f / 65536.0f));
}

// PASS 0: colsum[mat][k] += sum_b exp(L-40), full GEMM over all 4 matrices
__global__ __launch_bounds__(256, 2)
void pass0_kernel(const unsigned short* __restrict__ XA,  // [4][BH][DIM]
                  const unsigned short* __restrict__ Cn,  // [KC][DIM]
                  float* __restrict__ colsum) {
  __shared__ __align__(16) char lds[65536];
  // XCD-chunked swizzle: all 8 col-blocks of a row-panel on one XCD
  const int id  = blockIdx.x;            // 1024
  const int xcd = id & 7, idx = id >> 3;
  const int wk  = xcd * 128 + idx;       // 1024 % 8 == 0 -> bijective
  const int panel = wk >> 3, col = wk & 7;
  const int tm0 = panel * 128, tn0 = col * 128;

  const int tid  = threadIdx.x;
  const int lane = tid & 63;
  const int wid  = tid >> 6;
  const int wm   = wid >> 1, wn = wid & 1;
  const int l15  = lane & 15, l4 = lane >> 4;

  int arow[4], acs[4];
  #pragma unroll
  for (int it = 0; it < 4; ++it) {
    int slot = it * 256 + tid;
    int r = slot >> 3, c = slot & 7;
    arow[it] = r;
    acs[it]  = c ^ (r & 7);
  }
  const char* cb = (const char*)Cn;

  auto stage = [&](int t) {
    const int mat = t >> 2;
    const int bk  = t & 3;
    const int b   = t & 1;
    const char* ab = (const char*)XA + ((size_t)mat * BH + tm0) * 512;
    #pragma unroll
    for (int it = 0; it < 4; ++it) {
      gld_lds16(ab + (size_t)arow[it] * 512 + bk * 128 + acs[it] * 16,
                lds + b * 16384 + (it * 256 + tid) * 16);
      gld_lds16(cb + (size_t)(tn0 + arow[it]) * 512 + bk * 128 + acs[it] * 16,
                lds + 32768 + b * 16384 + (it * 256 + tid) * 16);
    }
  };

  f32x4 acc[4][4];
  stage(0);
  __syncthreads();

  for (int t = 0; t < 16; ++t) {
    if (t < 15) stage(t + 1);
    const int b = t & 1;
    const int mat = t >> 2, bk = t & 3;

    if (bk == 0) {
      #pragma unroll
      for (int fi = 0; fi < 4; ++fi)
        #pragma unroll
        for (int fj = 0; fj < 4; ++fj)
          acc[fi][fj] = (f32x4){0.f, 0.f, 0.f, 0.f};
    }

    #pragma unroll
    for (int kc = 0; kc < 2; ++kc) {
      bf16x8 aF[4], bF[4];
      #pragma unroll
      for (int f = 0; f < 4; ++f) {
        const int ra = wm * 64 + f * 16 + l15;
        aF[f] = *reinterpret_cast<const bf16x8*>(
            lds + b * 16384 + ra * 128 + ((((kc << 2) | l4) ^ (ra & 7)) << 4));
        const int rb = wn * 64 + f * 16 + l15;
        bF[f] = *reinterpret_cast<const bf16x8*>(
            lds + 32768 + b * 16384 + rb * 128 + ((((kc << 2) | l4) ^ (rb & 7)) << 4));
      }
      #pragma unroll
      for (int fi = 0; fi < 4; ++fi)
        #pragma unroll
        for (int fj = 0; fj < 4; ++fj)
          acc[fi][fj] = __builtin_amdgcn_mfma_f32_16x16x32_bf16(
              aF[fi], bF[fj], acc[fi][fj], 0, 0, 0);
    }

    if (bk == 3) {
      #pragma unroll
      for (int fj = 0; fj < 4; ++fj) {
        float cp = 0.0f;
        #pragma unroll
        for (int fi = 0; fi < 4; ++fi)
          #pragma unroll
          for (int i = 0; i < 4; ++i)
            cp += __expf(dist_L(acc[fi][fj][i]) - 40.0f);
        cp += __shfl_xor(cp, 16);
        cp += __shfl_xor(cp, 32);
        if (l4 == 0)
          atomicAdd(&colsum[mat * KC + tn0 + wn * 64 + fj * 16 + l15], cp);
      }
    }
    __syncthreads();
  }
}

// PASS 2': per (row-panel, k-quarter): for each col-tile, run p1,p2 (build
// tv = G_p1+G_p2, accumulate den_p), then z1,z2 (accumulate den_z, num_z).
__global__ __launch_bounds__(256, 2)
void pass2_kernel(const unsigned short* __restrict__ XA,
                  const unsigned short* __restrict__ Cn,
                  const float* __restrict__ logC,
                  float* __restrict__ rowAux) {
  __shared__ __align__(16) char lds[65536];
  const int id  = blockIdx.x;            // 512
  const int xcd = id & 7, idx = id >> 3;
  const int wk  = xcd * 64 + idx;        // 512 % 8 == 0 -> bijective
  const int panel = wk >> 2, ks = wk & 3;
  const int tm0 = panel * 128;

  const int tid  = threadIdx.x;
  const int lane = tid & 63;
  const int wid  = tid >> 6;
  const int wm   = wid >> 1, wn = wid & 1;
  const int l15  = lane & 15, l4 = lane >> 4;

  int arow[4], acs[4];
  #pragma unroll
  for (int it = 0; it < 4; ++it) {
    int slot = it * 256 + tid;
    int r = slot >> 3, c = slot & 7;
    arow[it] = r;
    acs[it]  = c ^ (r & 7);
  }

  // t = ct*16 + mi*4 + bk ; mat = (mi+2)&3 -> p1,p2,z1,z2
  auto stage = [&](int t) {
    const int ct = t >> 4, mi = (t >> 2) & 3, bk = t & 3, b = t & 1;
    const int mat = (mi + 2) & 3;
    const int ctg = ks * 2 + ct;
    const char* ab = (const char*)XA + ((size_t)mat * BH + tm0) * 512;
    const char* bb = (const char*)Cn + (size_t)ctg * 128 * 512;
    #pragma unroll
    for (int it = 0; it < 4; ++it) {
      gld_lds16(ab + (size_t)arow[it] * 512 + bk * 128 + acs[it] * 16,
                lds + b * 16384 + (it * 256 + tid) * 16);
      gld_lds16(bb + (size_t)arow[it] * 512 + bk * 128 + acs[it] * 16,
                lds + 32768 + b * 16384 + (it * 256 + tid) * 16);
    }
  };

  f32x4 acc[4][4];
  float tv[4][4][4];
  stage(0);
  __syncthreads();

  for (int t = 0; t < 32; ++t) {
    if (t < 31) stage(t + 1);
    const int b = t & 1;
    const int ct = t >> 4, mi = (t >> 2) & 3, bk = t & 3;
    const int mat = (mi + 2) & 3;
    const int ctg = ks * 2 + ct;

    if (bk == 0) {
      #pragma unroll
      for (int fi = 0; fi < 4; ++fi)
        #pragma unroll
        for (int fj = 0; fj < 4; ++fj)
          acc[fi][fj] = (f32x4){0.f, 0.f, 0.f, 0.f};
    }

    #pragma unroll
    for (int kc = 0; kc < 2; ++kc) {
      bf16x8 aF[4], bF[4];
      #pragma unroll
      for (int f = 0; f < 4; ++f) {
        const int ra = wm * 64 + f * 16 + l15;
        aF[f] = *reinterpret_cast<const bf16x8*>(
            lds + b * 16384 + ra * 128 + ((((kc << 2) | l4) ^ (ra & 7)) << 4));
        const int rb = wn * 64 + f * 16 + l15;
        bF[f] = *reinterpret_cast<const bf16x8*>(
            lds + 32768 + b * 16384 + rb * 128 + ((((kc << 2) | l4) ^ (rb & 7)) << 4));
      }
      #pragma unroll
      for (int fi = 0; fi < 4; ++fi)
        #pragma unroll
        for (int fj = 0; fj < 4; ++fj)
          acc[fi][fj] = __builtin_amdgcn_mfma_f32_16x16x32_bf16(
              aF[fi], bF[fj], acc[fi][fj], 0, 0, 0);
    }

    if (bk == 3) {
      float lc[4];
      #pragma unroll
      for (int fj = 0; fj < 4; ++fj)
        lc[fj] = logC[mat * KC + ctg * 128 + wn * 64 + fj * 16 + l15];

      if (mi < 2) {           // p1 / p2: build tv, accumulate den_p
        float rp[4][4];
        #pragma unroll
        for (int fi = 0; fi < 4; ++fi)
          #pragma unroll
          for (int i = 0; i < 4; ++i) rp[fi][i] = 0.0f;
        #pragma unroll
        for (int fi = 0; fi < 4; ++fi)
          #pragma unroll
          for (int fj = 0; fj < 4; ++fj)
            #pragma unroll
            for (int i = 0; i < 4; ++i) {
              float G = dist_L(acc[fi][fj][i]) - lc[fj];
              tv[fi][fj][i] = (mi == 0) ? G : (tv[fi][fj][i] + G);
              rp[fi][i] += __expf(G);
            }
        float* denP = rowAux + (size_t)mi * BH;
        #pragma unroll
        for (int fi = 0; fi < 4; ++fi)
          #pragma unroll
          for (int i = 0; i < 4; ++i) {
            float v = rp[fi][i];
            v += __shfl_xor(v, 1); v += __shfl_xor(v, 2);
            v += __shfl_xor(v, 4); v += __shfl_xor(v, 8);
            if (l15 == 0)
              atomicAdd(&denP[tm0 + wm * 64 + fi * 16 + l4 * 4 + i], v);
          }
      } else {                // z1 / z2: accumulate den_z and num_z
        float rd[4][4], rn[4][4];
        #pragma unroll
        for (int fi = 0; fi < 4; ++fi)
          #pragma unroll
          for (int i = 0; i < 4; ++i) { rd[fi][i] = 0.0f; rn[fi][i] = 0.0f; }
        #pragma unroll
        for (int fi = 0; fi < 4; ++fi)
          #pragma unroll
          for (int fj = 0; fj < 4; ++fj)
            #pragma unroll
            for (int i = 0; i < 4; ++i) {
              float G = dist_L(acc[fi][fj][i]) - lc[fj];
              float e = __expf(G);
              rd[fi][i] += e;
              rn[fi][i] += e * tv[fi][fj][i];
            }
        float* denZ = rowAux + (size_t)mi * BH;           // mi=2,3 -> denZ1,denZ2
        float* numZ = rowAux + (size_t)(mi + 2) * BH;     //        -> numZ1,numZ2
        #pragma unroll
        for (int fi = 0; fi < 4; ++fi)
          #pragma unroll
          for (int i = 0; i < 4; ++i) {
            float vd = rd[fi][i], vn = rn[fi][i];
            vd += __shfl_xor(vd, 1); vd += __shfl_xor(vd, 2);
            vd += __shfl_xor(vd, 4); vd += __shfl_xor(vd, 8);
            vn += __shfl_xor(vn, 1); vn += __shfl_xor(vn, 2);
            vn += __shfl_xor(vn, 4); vn += __shfl_xor(vn, 8);
            if (l15 == 0) {
              int row = tm0 + wm * 64 + fi * 16 + l4 * 4 + i;
              atomicAdd(&denZ[row], vd);
              atomicAdd(&numZ[row], vn);
            }
          }
      }
    }
    __syncthreads();
  }
}

extern "C" void kernel_launch(void* const* d_in, const int* in_sizes, int n_in,
                              void* d_out, int out_size, void* d_ws, size_t ws_size,
                              hipStream_t stream) {
  const float* z = (const float*)d_in[0];
  const float* p = (const float*)d_in[1];
  const float* c = (const float*)d_in[2];
  char* ws = (char*)d_ws;
  // layout: XA = [z1,z2,p1,p2] bf16 (33.55MB) | Cn 0.5MB | colsum | logC | rowAux
  unsigned short* Xn = (unsigned short*)(ws);
  unsigned short* Cn = (unsigned short*)(ws + 33554432);
  float* colsum = (float*)(ws + 34078720);
  float* logC   = (float*)(ws + 34095104);
  float* rowAux = (float*)(ws + 34111488);   // 6 * BH floats
  float* out = (float*)d_out;

  norm_rows_kernel<<<16640, 256, 0, stream>>>(z, p, c, Xn, Cn);
  zero_kernel<<<384, 256, 0, stream>>>(colsum, rowAux, out);

  pass0_kernel<<<1024, 256, 0, stream>>>(Xn, Cn, colsum);
  fin_logC_kernel<<<16, 256, 0, stream>>>(colsum, logC);
  pass2_kernel<<<512, 256, 0, stream>>>(Xn, Cn, logC, rowAux);
  fin_loss_kernel<<<64, 256, 0, stream>>>(rowAux, out);
}

// Round 4
// 222.029 us; speedup vs baseline: 2.1807x; 1.0013x over previous
//
#include <hip/hip_runtime.h>
#include <math.h>

#define BH  16384   // half batch
#define B2  32768
#define DIM 256
#define KC  1024    // clusters

typedef __bf16 bf16x8 __attribute__((ext_vector_type(8)));
typedef float  f32x4  __attribute__((ext_vector_type(4)));

__device__ __forceinline__ unsigned short f2bf(float f) {
  unsigned int u = __float_as_uint(f);
  u += 0x7FFFu + ((u >> 16) & 1u);   // RNE; inputs are finite
  return (unsigned short)(u >> 16);
}

__device__ __forceinline__ float vsqrt(float x) {
  float r; asm("v_sqrt_f32 %0, %1" : "=v"(r) : "v"(x)); return r;
}

__device__ __forceinline__ float dist_L(float dotv) {
  // L = D/eps = 20*sqrt(max(2-2*dot, 1e-12))
  return 20.0f * vsqrt(fmaxf(2.0f - 2.0f * dotv, 1e-12f));
}

__device__ __forceinline__ void gld_lds16(const void* g, void* l) {
  __builtin_amdgcn_global_load_lds(
      (const __attribute__((address_space(1))) void*)g,
      (__attribute__((address_space(3))) void*)l, 16, 0, 0);
}

// one wave per row: l2-normalize and convert to bf16
__global__ void norm_rows_kernel(const float* __restrict__ z,
                                 const float* __restrict__ p,
                                 const float* __restrict__ c,
                                 unsigned short* __restrict__ Xn,
                                 unsigned short* __restrict__ Cn) {
  int wave = threadIdx.x >> 6;
  int lane = threadIdx.x & 63;
  int row  = blockIdx.x * 4 + wave;          // 0 .. 66559
  const float* src; unsigned short* dst; int r;
  if (row < B2)        { src = z; dst = Xn; r = row; }
  else if (row < 2*B2) { src = p; dst = Xn + (size_t)B2 * DIM; r = row - B2; }
  else                 { src = c; dst = Cn; r = row - 2*B2; }
  float4 v = *reinterpret_cast<const float4*>(src + (size_t)r * DIM + lane * 4);
  float ss = v.x*v.x + v.y*v.y + v.z*v.z + v.w*v.w;
  #pragma unroll
  for (int m = 1; m < 64; m <<= 1) ss += __shfl_xor(ss, m);
  float inv = 1.0f / fmaxf(vsqrt(ss), 1e-12f);
  ushort4 o;
  o.x = f2bf(v.x * inv); o.y = f2bf(v.y * inv);
  o.z = f2bf(v.z * inv); o.w = f2bf(v.w * inv);
  *reinterpret_cast<ushort4*>(dst + (size_t)r * DIM + lane * 4) = o;
}

__global__ void zero_kernel(float* __restrict__ colsum,
                            float* __restrict__ rowAux,
                            float* __restrict__ out) {
  int i = blockIdx.x * 256 + threadIdx.x;
  if (i < 6 * BH) rowAux[i] = 0.0f;
  if (i < 4 * KC) colsum[i] = 0.0f;
  if (i == 0)     out[0]    = 0.0f;
}

__global__ void fin_logC_kernel(const float* __restrict__ colsum,
                                float* __restrict__ logC) {
  int i = blockIdx.x * 256 + threadIdx.x;
  if (i < 4 * KC) logC[i] = 40.0f + __logf(colsum[i]);
}

// loss = -(1/4B) * sum_b [num_z1/den_z1 + num_z2/den_z2 - 2(log den_p1 + log den_p2)]
__global__ void fin_loss_kernel(const float* __restrict__ rowAux,
                                float* __restrict__ out) {
  int i = blockIdx.x * 256 + threadIdx.x;   // 64 blocks x 256 = BH
  const float* denP1 = rowAux;
  const float* denP2 = rowAux + BH;
  const float* denZ1 = rowAux + 2 * BH;
  const float* denZ2 = rowAux + 3 * BH;
  const float* numZ1 = rowAux + 4 * BH;
  const float* numZ2 = rowAux + 5 * BH;
  float v = numZ1[i] / denZ1[i] + numZ2[i] / denZ2[i]
          - 2.0f * (__logf(denP1[i]) + __logf(denP2[i]));
  #pragma unroll
  for (int m = 1; m < 64; m <<= 1) v += __shfl_xor(v, m);
  __shared__ float ws[4];
  int lane = threadIdx.x & 63, wid = threadIdx.x >> 6;
  if (lane == 0) ws[wid] = v;
  __syncthreads();
  if (threadIdx.x == 0)
    atomicAdd(out, (ws[0] + ws[1] + ws[2] + ws[3]) * (-1.0f / 65536.0f));
}

// PASS 0: colsum[mat][k] += sum_b exp(L-40), full GEMM over all 4 matrices
__global__ __launch_bounds__(256, 2)
void pass0_kernel(const unsigned short* __restrict__ XA,  // [4][BH][DIM]
                  const unsigned short* __restrict__ Cn,  // [KC][DIM]
                  float* __restrict__ colsum) {
  __shared__ __align__(16) char lds[65536];
  // XCD-chunked swizzle: all 8 col-blocks of a row-panel on one XCD
  const int id  = blockIdx.x;            // 1024
  const int xcd = id & 7, idx = id >> 3;
  const int wk  = xcd * 128 + idx;       // 1024 % 8 == 0 -> bijective
  const int panel = wk >> 3, col = wk & 7;
  const int tm0 = panel * 128, tn0 = col * 128;

  const int tid  = threadIdx.x;
  const int lane = tid & 63;
  const int wid  = tid >> 6;
  const int wm   = wid >> 1, wn = wid & 1;
  const int l15  = lane & 15, l4 = lane >> 4;

  int arow[4], acs[4];
  #pragma unroll
  for (int it = 0; it < 4; ++it) {
    int slot = it * 256 + tid;
    int r = slot >> 3, c = slot & 7;
    arow[it] = r;
    acs[it]  = c ^ (r & 7);
  }
  const char* cb = (const char*)Cn;

  auto stage = [&](int t) {
    const int mat = t >> 2;
    const int bk  = t & 3;
    const int b   = t & 1;
    const char* ab = (const char*)XA + ((size_t)mat * BH + tm0) * 512;
    #pragma unroll
    for (int it = 0; it < 4; ++it) {
      gld_lds16(ab + (size_t)arow[it] * 512 + bk * 128 + acs[it] * 16,
                lds + b * 16384 + (it * 256 + tid) * 16);
      gld_lds16(cb + (size_t)(tn0 + arow[it]) * 512 + bk * 128 + acs[it] * 16,
                lds + 32768 + b * 16384 + (it * 256 + tid) * 16);
    }
  };

  f32x4 acc[4][4];
  stage(0);
  __syncthreads();

  for (int t = 0; t < 16; ++t) {
    if (t < 15) stage(t + 1);
    const int b = t & 1;
    const int mat = t >> 2, bk = t & 3;

    if (bk == 0) {
      #pragma unroll
      for (int fi = 0; fi < 4; ++fi)
        #pragma unroll
        for (int fj = 0; fj < 4; ++fj)
          acc[fi][fj] = (f32x4){0.f, 0.f, 0.f, 0.f};
    }

    #pragma unroll
    for (int kc = 0; kc < 2; ++kc) {
      bf16x8 aF[4], bF[4];
      #pragma unroll
      for (int f = 0; f < 4; ++f) {
        const int ra = wm * 64 + f * 16 + l15;
        aF[f] = *reinterpret_cast<const bf16x8*>(
            lds + b * 16384 + ra * 128 + ((((kc << 2) | l4) ^ (ra & 7)) << 4));
        const int rb = wn * 64 + f * 16 + l15;
        bF[f] = *reinterpret_cast<const bf16x8*>(
            lds + 32768 + b * 16384 + rb * 128 + ((((kc << 2) | l4) ^ (rb & 7)) << 4));
      }
      #pragma unroll
      for (int fi = 0; fi < 4; ++fi)
        #pragma unroll
        for (int fj = 0; fj < 4; ++fj)
          acc[fi][fj] = __builtin_amdgcn_mfma_f32_16x16x32_bf16(
              aF[fi], bF[fj], acc[fi][fj], 0, 0, 0);
    }

    if (bk == 3) {
      #pragma unroll
      for (int fj = 0; fj < 4; ++fj) {
        float cp = 0.0f;
        #pragma unroll
        for (int fi = 0; fi < 4; ++fi)
          #pragma unroll
          for (int i = 0; i < 4; ++i)
            cp += __expf(dist_L(acc[fi][fj][i]) - 40.0f);
        cp += __shfl_xor(cp, 16);
        cp += __shfl_xor(cp, 32);
        if (l4 == 0)
          atomicAdd(&colsum[mat * KC + tn0 + wn * 64 + fj * 16 + l15], cp);
      }
    }
    __syncthreads();
  }
}

// PASS 2': per (row-panel, k-quarter): for each col-tile, run p1,p2 (build
// tv = G_p1+G_p2, accumulate den_p), then z1,z2 (accumulate den_z, num_z).
__global__ __launch_bounds__(256, 2)
void pass2_kernel(const unsigned short* __restrict__ XA,
                  const unsigned short* __restrict__ Cn,
                  const float* __restrict__ logC,
                  float* __restrict__ rowAux) {
  __shared__ __align__(16) char lds[65536];
  const int id  = blockIdx.x;            // 512
  const int xcd = id & 7, idx = id >> 3;
  const int wk  = xcd * 64 + idx;        // 512 % 8 == 0 -> bijective
  const int panel = wk >> 2, ks = wk & 3;
  const int tm0 = panel * 128;

  const int tid  = threadIdx.x;
  const int lane = tid & 63;
  const int wid  = tid >> 6;
  const int wm   = wid >> 1, wn = wid & 1;
  const int l15  = lane & 15, l4 = lane >> 4;

  int arow[4], acs[4];
  #pragma unroll
  for (int it = 0; it < 4; ++it) {
    int slot = it * 256 + tid;
    int r = slot >> 3, c = slot & 7;
    arow[it] = r;
    acs[it]  = c ^ (r & 7);
  }

  // t = ct*16 + mi*4 + bk ; mat = (mi+2)&3 -> p1,p2,z1,z2
  auto stage = [&](int t) {
    const int ct = t >> 4, mi = (t >> 2) & 3, bk = t & 3, b = t & 1;
    const int mat = (mi + 2) & 3;
    const int ctg = ks * 2 + ct;
    const char* ab = (const char*)XA + ((size_t)mat * BH + tm0) * 512;
    const char* bb = (const char*)Cn + (size_t)ctg * 128 * 512;
    #pragma unroll
    for (int it = 0; it < 4; ++it) {
      gld_lds16(ab + (size_t)arow[it] * 512 + bk * 128 + acs[it] * 16,
                lds + b * 16384 + (it * 256 + tid) * 16);
      gld_lds16(bb + (size_t)arow[it] * 512 + bk * 128 + acs[it] * 16,
                lds + 32768 + b * 16384 + (it * 256 + tid) * 16);
    }
  };

  f32x4 acc[4][4];
  float tv[4][4][4];
  stage(0);
  __syncthreads();

  for (int t = 0; t < 32; ++t) {
    if (t < 31) stage(t + 1);
    const int b = t & 1;
    const int ct = t >> 4, mi = (t >> 2) & 3, bk = t & 3;
    const int mat = (mi + 2) & 3;
    const int ctg = ks * 2 + ct;

    if (bk == 0) {
      #pragma unroll
      for (int fi = 0; fi < 4; ++fi)
        #pragma unroll
        for (int fj = 0; fj < 4; ++fj)
          acc[fi][fj] = (f32x4){0.f, 0.f, 0.f, 0.f};
    }

    #pragma unroll
    for (int kc = 0; kc < 2; ++kc) {
      bf16x8 aF[4], bF[4];
      #pragma unroll
      for (int f = 0; f < 4; ++f) {
        const int ra = wm * 64 + f * 16 + l15;
        aF[f] = *reinterpret_cast<const bf16x8*>(
            lds + b * 16384 + ra * 128 + ((((kc << 2) | l4) ^ (ra & 7)) << 4));
        const int rb = wn * 64 + f * 16 + l15;
        bF[f] = *reinterpret_cast<const bf16x8*>(
            lds + 32768 + b * 16384 + rb * 128 + ((((kc << 2) | l4) ^ (rb & 7)) << 4));
      }
      #pragma unroll
      for (int fi = 0; fi < 4; ++fi)
        #pragma unroll
        for (int fj = 0; fj < 4; ++fj)
          acc[fi][fj] = __builtin_amdgcn_mfma_f32_16x16x32_bf16(
              aF[fi], bF[fj], acc[fi][fj], 0, 0, 0);
    }

    if (bk == 3) {
      float lc[4];
      #pragma unroll
      for (int fj = 0; fj < 4; ++fj)
        lc[fj] = logC[mat * KC + ctg * 128 + wn * 64 + fj * 16 + l15];

      if (mi < 2) {           // p1 / p2: build tv, accumulate den_p
        float rp[4][4];
        #pragma unroll
        for (int fi = 0; fi < 4; ++fi)
          #pragma unroll
          for (int i = 0; i < 4; ++i) rp[fi][i] = 0.0f;
        #pragma unroll
        for (int fi = 0; fi < 4; ++fi)
          #pragma unroll
          for (int fj = 0; fj < 4; ++fj)
            #pragma unroll
            for (int i = 0; i < 4; ++i) {
              float G = dist_L(acc[fi][fj][i]) - lc[fj];
              tv[fi][fj][i] = (mi == 0) ? G : (tv[fi][fj][i] + G);
              rp[fi][i] += __expf(G);
            }
        float* denP = rowAux + (size_t)mi * BH;
        #pragma unroll
        for (int fi = 0; fi < 4; ++fi)
          #pragma unroll
          for (int i = 0; i < 4; ++i) {
            float v = rp[fi][i];
            v += __shfl_xor(v, 1); v += __shfl_xor(v, 2);
            v += __shfl_xor(v, 4); v += __shfl_xor(v, 8);
            if (l15 == 0)
              atomicAdd(&denP[tm0 + wm * 64 + fi * 16 + l4 * 4 + i], v);
          }
      } else {                // z1 / z2: accumulate den_z and num_z
        float rd[4][4], rn[4][4];
        #pragma unroll
        for (int fi = 0; fi < 4; ++fi)
          #pragma unroll
          for (int i = 0; i < 4; ++i) { rd[fi][i] = 0.0f; rn[fi][i] = 0.0f; }
        #pragma unroll
        for (int fi = 0; fi < 4; ++fi)
          #pragma unroll
          for (int fj = 0; fj < 4; ++fj)
            #pragma unroll
            for (int i = 0; i < 4; ++i) {
              float G = dist_L(acc[fi][fj][i]) - lc[fj];
              float e = __expf(G);
              rd[fi][i] += e;
              rn[fi][i] += e * tv[fi][fj][i];
            }
        float* denZ = rowAux + (size_t)mi * BH;           // mi=2,3 -> denZ1,denZ2
        float* numZ = rowAux + (size_t)(mi + 2) * BH;     //        -> numZ1,numZ2
        #pragma unroll
        for (int fi = 0; fi < 4; ++fi)
          #pragma unroll
          for (int i = 0; i < 4; ++i) {
            float vd = rd[fi][i], vn = rn[fi][i];
            vd += __shfl_xor(vd, 1); vd += __shfl_xor(vd, 2);
            vd += __shfl_xor(vd, 4); vd += __shfl_xor(vd, 8);
            vn += __shfl_xor(vn, 1); vn += __shfl_xor(vn, 2);
            vn += __shfl_xor(vn, 4); vn += __shfl_xor(vn, 8);
            if (l15 == 0) {
              int row = tm0 + wm * 64 + fi * 16 + l4 * 4 + i;
              atomicAdd(&denZ[row], vd);
              atomicAdd(&numZ[row], vn);
            }
          }
      }
    }
    __syncthreads();
  }
}

extern "C" void kernel_launch(void* const* d_in, const int* in_sizes, int n_in,
                              void* d_out, int out_size, void* d_ws, size_t ws_size,
                              hipStream_t stream) {
  const float* z = (const float*)d_in[0];
  const float* p = (const float*)d_in[1];
  const float* c = (const float*)d_in[2];
  char* ws = (char*)d_ws;
  // layout: XA = [z1,z2,p1,p2] bf16 (33.55MB) | Cn 0.5MB | colsum | logC | rowAux
  unsigned short* Xn = (unsigned short*)(ws);
  unsigned short* Cn = (unsigned short*)(ws + 33554432);
  float* colsum = (float*)(ws + 34078720);
  float* logC   = (float*)(ws + 34095104);
  float* rowAux = (float*)(ws + 34111488);   // 6 * BH floats
  float* out = (float*)d_out;

  norm_rows_kernel<<<16640, 256, 0, stream>>>(z, p, c, Xn, Cn);
  zero_kernel<<<384, 256, 0, stream>>>(colsum, rowAux, out);

  pass0_kernel<<<1024, 256, 0, stream>>>(Xn, Cn, colsum);
  fin_logC_kernel<<<16, 256, 0, stream>>>(colsum, logC);
  pass2_kernel<<<512, 256, 0, stream>>>(Xn, Cn, logC, rowAux);
  fin_loss_kernel<<<64, 256, 0, stream>>>(rowAux, out);
}